// Round 3
// baseline (68352.258 us; speedup 1.0000x reference)
//
#include <hip/hip_runtime.h>
#include <math.h>

// SynchronGRU: 8-layer Keras-v2 GRU (reset_after=True), B=512 T=256 F=8 U=128.
// Persistent-weights design: thread n<384 holds fp32 input-kernel column n,
// thread 384+n holds recurrent-kernel column n. Activations broadcast via LDS.
// 2 batch rows per block, 256 blocks (1/CU), 768 threads (12 waves).
//
// R1/R2 lesson: `float w[128]` stayed a scratch alloca (SROA can't scalarize
// variable-index arrays; launch_bounds doesn't help) -> 163 GB scratch traffic,
// 58 ms. Fix: 32 NAMED float4 registers via X-macro, constant-member access
// only. These cannot live in scratch short of allocator spill.

namespace {

constexpr int kB = 512;
constexpr int kT = 256;
constexpr int kF = 8;
constexpr int kU = 128;
constexpr int kG = 384;   // 3*U, gate order [z, r, h]
constexpr int kL = 8;
constexpr int kRows = 2;  // batch rows per block
constexpr int kThreads = 2 * kG;  // 768 = 12 waves

// X-macro over the 32 float4 weight registers
#define W_FOREACH(X) \
  X(0) X(1) X(2) X(3) X(4) X(5) X(6) X(7) \
  X(8) X(9) X(10) X(11) X(12) X(13) X(14) X(15) \
  X(16) X(17) X(18) X(19) X(20) X(21) X(22) X(23) \
  X(24) X(25) X(26) X(27) X(28) X(29) X(30) X(31)

__global__ __launch_bounds__(kThreads, 3) void gru_all(
    const float* __restrict__ xin,      // (B,T,F)
    const float* __restrict__ init_h,   // (L,B,U)
    const float* __restrict__ kernel0,  // (F,3U)
    const float* __restrict__ kernels,  // (L-1,U,3U)
    const float* __restrict__ rec_k,    // (L,U,3U)
    const float* __restrict__ biases,   // (L,2,3U)
    float* __restrict__ out)            // (B,T,U) seq out | (L,B,U) states
{
    __shared__ __align__(16) float xbuf[kRows][kU];
    __shared__ __align__(16) float hbuf[kRows][kU];
    __shared__ float xacc[kRows][kG];
    __shared__ float hacc[kRows][kG];

    const int tid  = threadIdx.x;
    const int b0   = blockIdx.x * kRows;
    const bool is_x = tid < kG;             // wave-uniform (384 = 6 waves)
    const int col  = is_x ? tid : tid - kG; // weight column owned

    const int ru_r = (tid >> 7) & 1;  // valid for tid < 256
    const int ru_u = tid & 127;

    float* __restrict__ buf    = out;                        // in-place activations
    float* __restrict__ states = out + (size_t)kB * kT * kU; // final h per layer

    for (int l = 0; l < kL; ++l) {
        // ---- weight column + bias into NAMED registers ----
#define DECLW(i) float4 w##i = {0.f, 0.f, 0.f, 0.f};
        W_FOREACH(DECLW)
#undef DECLW
        float bias_reg;
        if (is_x) {
            bias_reg = biases[l * 2 * kG + col];
            if (l == 0) {
                // only 8 k-values: w0, w1
                w0.x = kernel0[0 * kG + col]; w0.y = kernel0[1 * kG + col];
                w0.z = kernel0[2 * kG + col]; w0.w = kernel0[3 * kG + col];
                w1.x = kernel0[4 * kG + col]; w1.y = kernel0[5 * kG + col];
                w1.z = kernel0[6 * kG + col]; w1.w = kernel0[7 * kG + col];
            } else {
                const float* Wp = kernels + (size_t)(l - 1) * kU * kG + col;
#define LOADW(i) w##i.x = Wp[(size_t)(4*i+0)*kG]; w##i.y = Wp[(size_t)(4*i+1)*kG]; \
                 w##i.z = Wp[(size_t)(4*i+2)*kG]; w##i.w = Wp[(size_t)(4*i+3)*kG];
                W_FOREACH(LOADW)
#undef LOADW
            }
        } else {
            bias_reg = biases[l * 2 * kG + kG + col];
            const float* Wp = rec_k + (size_t)l * kU * kG + col;
#define LOADW(i) w##i.x = Wp[(size_t)(4*i+0)*kG]; w##i.y = Wp[(size_t)(4*i+1)*kG]; \
                 w##i.z = Wp[(size_t)(4*i+2)*kG]; w##i.w = Wp[(size_t)(4*i+3)*kG];
            W_FOREACH(LOADW)
#undef LOADW
        }
        // ---- init h ----
        if (tid < kRows * kU) {
            hbuf[ru_r][ru_u] = init_h[(size_t)l * kB * kU + (size_t)(b0 + ru_r) * kU + ru_u];
        }
        __syncthreads();

        for (int t = 0; t < kT; ++t) {
            // ---- stage x_t into LDS ----
            if (l == 0) {
                if (tid < kRows * kF) {
                    const int r = tid >> 3, k = tid & 7;
                    xbuf[r][k] = xin[((size_t)(b0 + r) * kT + t) * kF + k];
                }
            } else {
                if (tid < kRows * kU) {
                    xbuf[ru_r][ru_u] = buf[((size_t)(b0 + ru_r) * kT + t) * kU + ru_u];
                }
            }
            __syncthreads();

            // ---- dot products: x@Wk (waves 0-5) and h@Wr (waves 6-11) ----
            {
                float a0 = bias_reg, a1 = bias_reg;
                if (is_x && l == 0) {
                    a0 += xbuf[0][0]*w0.x + xbuf[0][1]*w0.y + xbuf[0][2]*w0.z + xbuf[0][3]*w0.w
                        + xbuf[0][4]*w1.x + xbuf[0][5]*w1.y + xbuf[0][6]*w1.z + xbuf[0][7]*w1.w;
                    a1 += xbuf[1][0]*w0.x + xbuf[1][1]*w0.y + xbuf[1][2]*w0.z + xbuf[1][3]*w0.w
                        + xbuf[1][4]*w1.x + xbuf[1][5]*w1.y + xbuf[1][6]*w1.z + xbuf[1][7]*w1.w;
                } else {
                    const float4* v0 = (const float4*)(is_x ? xbuf[0] : hbuf[0]);
                    const float4* v1 = (const float4*)(is_x ? xbuf[1] : hbuf[1]);
                    float p0 = 0.f, p1 = 0.f;  // second accumulation chains (ILP)
#define DOT(i) { const float4 c0 = v0[i]; const float4 c1 = v1[i];          \
                 a0 += c0.x * w##i.x; p0 += c0.y * w##i.y;                  \
                 a0 += c0.z * w##i.z; p0 += c0.w * w##i.w;                  \
                 a1 += c1.x * w##i.x; p1 += c1.y * w##i.y;                  \
                 a1 += c1.z * w##i.z; p1 += c1.w * w##i.w; }
                    W_FOREACH(DOT)
#undef DOT
                    a0 += p0; a1 += p1;
                }
                if (is_x) { xacc[0][col] = a0; xacc[1][col] = a1; }
                else      { hacc[0][col] = a0; hacc[1][col] = a1; }
            }
            __syncthreads();

            // ---- gates + state update (threads 0..255 = (row, unit)) ----
            if (tid < kRows * kU) {
                const int r = ru_r, u = ru_u;
                const float xz = xacc[r][u],          hz = hacc[r][u];
                const float xr = xacc[r][kU + u],     hr = hacc[r][kU + u];
                const float xh = xacc[r][2 * kU + u], hp = hacc[r][2 * kU + u];
                const float z  = 1.f / (1.f + __expf(-(xz + hz)));
                const float rr = 1.f / (1.f + __expf(-(xr + hr)));
                const float hh = tanhf(xh + rr * hp);
                const float h  = z * hbuf[r][u] + (1.f - z) * hh;
                hbuf[r][u] = h;
                buf[((size_t)(b0 + r) * kT + t) * kU + u] = h;  // layer output (in-place)
            }
            __syncthreads();  // hbuf ready for next step's h-dot
        }

        // ---- final state of this layer ----
        if (tid < kRows * kU) {
            states[(size_t)l * kB * kU + (size_t)(b0 + ru_r) * kU + ru_u] = hbuf[ru_r][ru_u];
        }
        __syncthreads();
    }
}

}  // namespace

extern "C" void kernel_launch(void* const* d_in, const int* in_sizes, int n_in,
                              void* d_out, int out_size, void* d_ws, size_t ws_size,
                              hipStream_t stream) {
    const float* xin     = (const float*)d_in[0];
    const float* init_h  = (const float*)d_in[1];
    const float* kernel0 = (const float*)d_in[2];
    const float* kernels = (const float*)d_in[3];
    const float* rec_k   = (const float*)d_in[4];
    const float* biases  = (const float*)d_in[5];
    float* out = (float*)d_out;

    dim3 grid(kB / kRows);   // 256 blocks -> 1 per CU
    dim3 block(kThreads);    // 768 threads = 12 waves
    gru_all<<<grid, block, 0, stream>>>(xin, init_h, kernel0, kernels, rec_k, biases, out);
}

// Round 4
// 67327.985 us; speedup vs baseline: 1.0152x; 1.0152x over previous
//
#include <hip/hip_runtime.h>
#include <math.h>

// SynchronGRU: 8-layer Keras-v2 GRU (reset_after=True), B=512 T=256 F=8 U=128.
// Persistent-weights design: thread n<384 holds fp32 input-kernel column n,
// thread 384+n holds recurrent-kernel column n (32 named float4 regs each).
// Activations broadcast via LDS. 2 batch rows/block, 256 blocks, 768 threads.
//
// R1-R3 lesson: __launch_bounds__(768,3) only sets MIN waves/EU; the backend
// still targeted 6 waves/EU (2 blocks/CU, 85-VGPR budget) and spilled all 128
// weight regs -> 164 GB scratch reloads, 58-65 ms, VGPR_Count=84.
// Fix: amdgpu_waves_per_eu(3,3) clamps occupancy to exactly 3 waves/EU
// (1 block/CU) so the RA budget is ~170 VGPRs and weights stay resident.

namespace {

constexpr int kB = 512;
constexpr int kT = 256;
constexpr int kF = 8;
constexpr int kU = 128;
constexpr int kG = 384;   // 3*U, gate order [z, r, h]
constexpr int kL = 8;
constexpr int kRows = 2;  // batch rows per block
constexpr int kThreads = 2 * kG;  // 768 = 12 waves

// X-macro over the 32 float4 weight registers
#define W_FOREACH(X) \
  X(0) X(1) X(2) X(3) X(4) X(5) X(6) X(7) \
  X(8) X(9) X(10) X(11) X(12) X(13) X(14) X(15) \
  X(16) X(17) X(18) X(19) X(20) X(21) X(22) X(23) \
  X(24) X(25) X(26) X(27) X(28) X(29) X(30) X(31)

__global__
__attribute__((amdgpu_flat_work_group_size(kThreads, kThreads),
               amdgpu_waves_per_eu(3, 3)))
void gru_all(
    const float* __restrict__ xin,      // (B,T,F)
    const float* __restrict__ init_h,   // (L,B,U)
    const float* __restrict__ kernel0,  // (F,3U)
    const float* __restrict__ kernels,  // (L-1,U,3U)
    const float* __restrict__ rec_k,    // (L,U,3U)
    const float* __restrict__ biases,   // (L,2,3U)
    float* __restrict__ out)            // (B,T,U) seq out | (L,B,U) states
{
    __shared__ __align__(16) float xbuf[kRows][kU];
    __shared__ __align__(16) float hbuf[kRows][kU];
    __shared__ float xacc[kRows][kG];
    __shared__ float hacc[kRows][kG];

    const int tid  = threadIdx.x;
    const int b0   = blockIdx.x * kRows;
    const bool is_x = tid < kG;             // wave-uniform (384 = 6 waves)
    const int col  = is_x ? tid : tid - kG; // weight column owned

    const int ru_r = (tid >> 7) & 1;  // valid for tid < 256
    const int ru_u = tid & 127;

    float* __restrict__ buf    = out;                        // in-place activations
    float* __restrict__ states = out + (size_t)kB * kT * kU; // final h per layer

    for (int l = 0; l < kL; ++l) {
        // ---- weight column + bias into NAMED registers ----
#define DECLW(i) float4 w##i = {0.f, 0.f, 0.f, 0.f};
        W_FOREACH(DECLW)
#undef DECLW
        float bias_reg;
        if (is_x) {
            bias_reg = biases[l * 2 * kG + col];
            if (l == 0) {
                // only 8 k-values: w0, w1
                w0.x = kernel0[0 * kG + col]; w0.y = kernel0[1 * kG + col];
                w0.z = kernel0[2 * kG + col]; w0.w = kernel0[3 * kG + col];
                w1.x = kernel0[4 * kG + col]; w1.y = kernel0[5 * kG + col];
                w1.z = kernel0[6 * kG + col]; w1.w = kernel0[7 * kG + col];
            } else {
                const float* Wp = kernels + (size_t)(l - 1) * kU * kG + col;
#define LOADW(i) w##i.x = Wp[(size_t)(4*i+0)*kG]; w##i.y = Wp[(size_t)(4*i+1)*kG]; \
                 w##i.z = Wp[(size_t)(4*i+2)*kG]; w##i.w = Wp[(size_t)(4*i+3)*kG];
                W_FOREACH(LOADW)
#undef LOADW
            }
        } else {
            bias_reg = biases[l * 2 * kG + kG + col];
            const float* Wp = rec_k + (size_t)l * kU * kG + col;
#define LOADW(i) w##i.x = Wp[(size_t)(4*i+0)*kG]; w##i.y = Wp[(size_t)(4*i+1)*kG]; \
                 w##i.z = Wp[(size_t)(4*i+2)*kG]; w##i.w = Wp[(size_t)(4*i+3)*kG];
            W_FOREACH(LOADW)
#undef LOADW
        }
        // ---- init h ----
        if (tid < kRows * kU) {
            hbuf[ru_r][ru_u] = init_h[(size_t)l * kB * kU + (size_t)(b0 + ru_r) * kU + ru_u];
        }
        __syncthreads();

        for (int t = 0; t < kT; ++t) {
            // ---- stage x_t into LDS ----
            if (l == 0) {
                if (tid < kRows * kF) {
                    const int r = tid >> 3, k = tid & 7;
                    xbuf[r][k] = xin[((size_t)(b0 + r) * kT + t) * kF + k];
                }
            } else {
                if (tid < kRows * kU) {
                    xbuf[ru_r][ru_u] = buf[((size_t)(b0 + ru_r) * kT + t) * kU + ru_u];
                }
            }
            __syncthreads();

            // ---- dot products: x@Wk (waves 0-5) and h@Wr (waves 6-11) ----
            {
                float a0 = bias_reg, a1 = bias_reg;
                if (is_x && l == 0) {
                    a0 += xbuf[0][0]*w0.x + xbuf[0][1]*w0.y + xbuf[0][2]*w0.z + xbuf[0][3]*w0.w
                        + xbuf[0][4]*w1.x + xbuf[0][5]*w1.y + xbuf[0][6]*w1.z + xbuf[0][7]*w1.w;
                    a1 += xbuf[1][0]*w0.x + xbuf[1][1]*w0.y + xbuf[1][2]*w0.z + xbuf[1][3]*w0.w
                        + xbuf[1][4]*w1.x + xbuf[1][5]*w1.y + xbuf[1][6]*w1.z + xbuf[1][7]*w1.w;
                } else {
                    const float4* v0 = (const float4*)(is_x ? xbuf[0] : hbuf[0]);
                    const float4* v1 = (const float4*)(is_x ? xbuf[1] : hbuf[1]);
                    float p0 = 0.f, p1 = 0.f;  // second accumulation chains (ILP)
#define DOT(i) { const float4 c0 = v0[i]; const float4 c1 = v1[i];          \
                 a0 += c0.x * w##i.x; p0 += c0.y * w##i.y;                  \
                 a0 += c0.z * w##i.z; p0 += c0.w * w##i.w;                  \
                 a1 += c1.x * w##i.x; p1 += c1.y * w##i.y;                  \
                 a1 += c1.z * w##i.z; p1 += c1.w * w##i.w; }
                    W_FOREACH(DOT)
#undef DOT
                    a0 += p0; a1 += p1;
                }
                if (is_x) { xacc[0][col] = a0; xacc[1][col] = a1; }
                else      { hacc[0][col] = a0; hacc[1][col] = a1; }
            }
            __syncthreads();

            // ---- gates + state update (threads 0..255 = (row, unit)) ----
            if (tid < kRows * kU) {
                const int r = ru_r, u = ru_u;
                const float xz = xacc[r][u],          hz = hacc[r][u];
                const float xr = xacc[r][kU + u],     hr = hacc[r][kU + u];
                const float xh = xacc[r][2 * kU + u], hp = hacc[r][2 * kU + u];
                const float z  = 1.f / (1.f + __expf(-(xz + hz)));
                const float rr = 1.f / (1.f + __expf(-(xr + hr)));
                const float hh = tanhf(xh + rr * hp);
                const float h  = z * hbuf[r][u] + (1.f - z) * hh;
                hbuf[r][u] = h;
                buf[((size_t)(b0 + r) * kT + t) * kU + u] = h;  // layer output (in-place)
            }
            __syncthreads();  // hbuf ready for next step's h-dot
        }

        // ---- final state of this layer ----
        if (tid < kRows * kU) {
            states[(size_t)l * kB * kU + (size_t)(b0 + ru_r) * kU + ru_u] = hbuf[ru_r][ru_u];
        }
        __syncthreads();
    }
}

}  // namespace

extern "C" void kernel_launch(void* const* d_in, const int* in_sizes, int n_in,
                              void* d_out, int out_size, void* d_ws, size_t ws_size,
                              hipStream_t stream) {
    const float* xin     = (const float*)d_in[0];
    const float* init_h  = (const float*)d_in[1];
    const float* kernel0 = (const float*)d_in[2];
    const float* kernels = (const float*)d_in[3];
    const float* rec_k   = (const float*)d_in[4];
    const float* biases  = (const float*)d_in[5];
    float* out = (float*)d_out;

    dim3 grid(kB / kRows);   // 256 blocks -> 1 per CU
    dim3 block(kThreads);    // 768 threads = 12 waves
    gru_all<<<grid, block, 0, stream>>>(xin, init_h, kernel0, kernels, rec_k, biases, out);
}